// Round 1
// baseline (1500.782 us; speedup 1.0000x reference)
//
#include <hip/hip_runtime.h>

// ---------------------------------------------------------------------------
// Fused: conv(2x2 s2) -> lrelu -> conv3x3 -> lrelu -> conv3x3 -> lrelu ->
//        stem linear + v_proj -> lrelu -> GRUCell -> (act = lrelu(hx')@Wfc, hx')
// B=65536. All matmul-shaped stages via mfma_f32_16x16x32_bf16 (fp32 acc).
// One wg = 256 threads = 4 waves = 16 samples; conv stages in 4-sample chunks.
// LDS 57344 B -> 2 wgs/CU. Waves partition N so weights stream once per wg.
// ---------------------------------------------------------------------------

typedef short bf8 __attribute__((ext_vector_type(8)));   // 8 x bf16 (4 VGPR)
typedef float f4  __attribute__((ext_vector_type(4)));   // MFMA C/D

#define MFMA(a, b, c) __builtin_amdgcn_mfma_f32_16x16x32_bf16(a, b, c, 0, 0, 0)

__device__ __forceinline__ unsigned short f2bf(float f) {
    unsigned int u = __float_as_uint(f);
    u += 0x7fffu + ((u >> 16) & 1u);          // RNE
    return (unsigned short)(u >> 16);
}
__device__ __forceinline__ float bf2f(unsigned short h) {
    return __uint_as_float(((unsigned int)h) << 16);
}
__device__ __forceinline__ float lrelu(float v) { return v > 0.f ? v : 0.05f * v; }
__device__ __forceinline__ float sigm(float x) { return 1.f / (1.f + __expf(-x)); }
__device__ __forceinline__ float tanh_(float x) {
    float e = __expf(2.f * x);                // inf-safe: x>>0 -> 1, x<<0 -> -1
    return 1.f - 2.f / (e + 1.f);
}
// swizzle for C2 region (adds q-bit6 so conv3 A-reads spread banks)
__device__ __forceinline__ int swzC(int q, int s) {
    return q ^ ((s & 3) << 3) ^ ((q >> 1) & 32);
}

// ---- weight prep: fp32 -> bf16 with K-permutation, into d_ws --------------
// ws layout (bf16 elems):
//   [0,18432)        w2p   [64][288]   k=(ky*3+kx)*32+ci
//   [18432,92160)    w3p   [128][576]  k=(ky*3+kx)*64+ci
//   [92160,288768)   wstem [192][1024] k=pos*128+ci   (pos = y*4+x of conv3 out)
//   [288768,399360)  w_ih  [576][192]
//   [399360,509952)  w_hh  [576][192]
__global__ void prep_weights(const float* __restrict__ w2, const float* __restrict__ w3,
                             const float* __restrict__ wstem, const float* __restrict__ wih,
                             const float* __restrict__ whh, unsigned short* __restrict__ o) {
    int i = blockIdx.x * 256 + threadIdx.x;
    if (i >= 509952) return;
    float val;
    if (i < 18432) {
        int n = i / 288, k = i - n * 288;
        val = w2[n * 288 + (k & 31) * 9 + (k >> 5)];
    } else if (i < 92160) {
        int d = i - 18432;
        int n = d / 576, k = d - n * 576;
        val = w3[n * 576 + (k & 63) * 9 + (k >> 6)];
    } else if (i < 288768) {
        int d = i - 92160;
        int n = d >> 10, k = d & 1023;
        val = wstem[(n << 10) + (k & 127) * 8 + (k >> 7)];
    } else if (i < 399360) {
        val = wih[i - 288768];
    } else {
        val = whh[i - 399360];
    }
    o[i] = f2bf(val);
}

// ---- fused model ----------------------------------------------------------
// LDS (shorts): C1=[0,6144) 4 samp x1536 | C2=[6144,12288) 4x1536 |
//               C3=[12288,28672) 16x1024 | reuse: FUSED=[0,3072) HX=[3072,6144)
//               LRL=[6144,9216)
__global__ __launch_bounds__(256, 2) void fused_model(
    const float* __restrict__ x, const float* __restrict__ v,
    const float* __restrict__ hx, const float* __restrict__ w1,
    const float* __restrict__ wvp, const float* __restrict__ bvp,
    const float* __restrict__ bih, const float* __restrict__ bhh,
    const float* __restrict__ wfc, const unsigned short* __restrict__ ws,
    float* __restrict__ out)
{
    __shared__ __align__(16) unsigned short lds[28672];
    const int tid = threadIdx.x;
    const int wave = tid >> 6, lane = tid & 63;
    const int col = lane & 15, quad = lane >> 4;
    const int S0 = blockIdx.x * 16;

    // ================= conv pipeline, 4 chunks of 4 samples =================
    for (int c = 0; c < 4; ++c) {
        // ---- conv1: 2x2 stride2, 1->32ch, out [s][y6][x8][co32] bf16 in C1
        if (tid < 192) {
            int s = tid / 48, p = tid - s * 48;          // p = y*8+xx
            int y = p >> 3, xx = p & 7;
            const float* xp = x + (S0 + c * 4 + s) * 192 + y * 32 + xx * 2;
            float x00 = xp[0], x01 = xp[1], x10 = xp[16], x11 = xp[17];
            int base = s * 1536, sw = (s & 3) << 3;
            #pragma unroll
            for (int co = 0; co < 32; ++co) {
                float a = x00 * w1[co * 4] + x01 * w1[co * 4 + 1]
                        + x10 * w1[co * 4 + 2] + x11 * w1[co * 4 + 3];
                int q = p * 32 + co;
                lds[base + (q ^ sw)] = f2bf(lrelu(a));
            }
        }
        __syncthreads();

        // ---- conv2: M=96 (m=pos*4+s, pos<24), N=64 (wave->n0), K=288
        {
            int n0 = wave * 16;
            bf8 Bf[9];
            int kq[9];
            #pragma unroll
            for (int ks = 0; ks < 9; ++ks) {
                Bf[ks] = *(const bf8*)(ws + (n0 + col) * 288 + ks * 32 + quad * 8);
                int k0 = ks * 32 + quad * 8;
                int ky = k0 / 96, r = k0 - 96 * ky;
                kq[ks] = (ky * 8 + (r >> 5)) * 32 + (r & 31);
            }
            #pragma unroll
            for (int mt2 = 0; mt2 < 3; ++mt2) {
                int m0 = mt2 * 32 + col, m1 = m0 + 16;
                int s0 = m0 & 3, p0 = m0 >> 2;
                int s1 = m1 & 3, p1 = m1 >> 2;
                int oy0 = p0 / 6, ox0 = p0 - 6 * oy0;
                int oy1 = p1 / 6, ox1 = p1 - 6 * oy1;
                int b0 = s0 * 1536, qb0 = (oy0 * 8 + ox0) * 32, sw0 = (s0 & 3) << 3;
                int b1 = s1 * 1536, qb1 = (oy1 * 8 + ox1) * 32, sw1 = (s1 & 3) << 3;
                f4 acc0 = {0.f, 0.f, 0.f, 0.f}, acc1 = {0.f, 0.f, 0.f, 0.f};
                #pragma unroll
                for (int ks = 0; ks < 9; ++ks) {
                    bf8 a0 = *(const bf8*)&lds[b0 + ((qb0 + kq[ks]) ^ sw0)];
                    bf8 a1 = *(const bf8*)&lds[b1 + ((qb1 + kq[ks]) ^ sw1)];
                    acc0 = MFMA(a0, Bf[ks], acc0);
                    acc1 = MFMA(a1, Bf[ks], acc1);
                }
                // epilogue -> C2 [s][y4][x6][ci64], swizzled
                #pragma unroll
                for (int r = 0; r < 4; ++r) {
                    int m = mt2 * 32 + quad * 4 + r;
                    int s = m & 3, pos = m >> 2;
                    int q = pos * 64 + n0 + col;
                    lds[6144 + s * 1536 + swzC(q, s)] = f2bf(lrelu(acc0[r]));
                    m += 16; s = m & 3; pos = m >> 2;
                    q = pos * 64 + n0 + col;
                    lds[6144 + s * 1536 + swzC(q, s)] = f2bf(lrelu(acc1[r]));
                }
            }
        }
        __syncthreads();

        // ---- conv3: M=32 (m=pos*4+s, pos<8), N=128 (wave->2 ntiles), K=576
        {
            int kq3[18];
            #pragma unroll
            for (int ks = 0; ks < 18; ++ks) {
                int k0 = ks * 32 + quad * 8;
                int ky = k0 / 192, r = k0 - 192 * ky;
                kq3[ks] = (ky * 6 + (r >> 6)) * 64 + (r & 63);
            }
            int m0 = col, m1 = 16 + col;
            int s0 = m0 & 3, p0 = m0 >> 2;
            int s1 = m1 & 3, p1 = m1 >> 2;
            int qb0 = ((p0 >> 2) * 6 + (p0 & 3)) * 64;   // pos = oy*4+ox, in-map W=6
            int qb1 = ((p1 >> 2) * 6 + (p1 & 3)) * 64;
            int b0 = 6144 + s0 * 1536, b1 = 6144 + s1 * 1536;
            #pragma unroll
            for (int ntl = 0; ntl < 2; ++ntl) {
                int n0 = (wave * 2 + ntl) * 16;
                bf8 Bf[18];
                #pragma unroll
                for (int ks = 0; ks < 18; ++ks)
                    Bf[ks] = *(const bf8*)(ws + 18432 + (n0 + col) * 576 + ks * 32 + quad * 8);
                f4 acc0 = {0.f, 0.f, 0.f, 0.f}, acc1 = {0.f, 0.f, 0.f, 0.f};
                #pragma unroll
                for (int ks = 0; ks < 18; ++ks) {
                    bf8 a0 = *(const bf8*)&lds[b0 + swzC(qb0 + kq3[ks], s0)];
                    bf8 a1 = *(const bf8*)&lds[b1 + swzC(qb1 + kq3[ks], s1)];
                    acc0 = MFMA(a0, Bf[ks], acc0);
                    acc1 = MFMA(a1, Bf[ks], acc1);
                }
                // epilogue -> C3 [sl16][pos8*128+ci], swizzled by sl&7
                #pragma unroll
                for (int r = 0; r < 4; ++r) {
                    int m = quad * 4 + r;
                    int s = m & 3, pos = m >> 2, sl = c * 4 + s;
                    int q = pos * 128 + n0 + col;
                    lds[12288 + sl * 1024 + (q ^ ((sl & 7) << 3))] = f2bf(lrelu(acc0[r]));
                    m += 16; s = m & 3; pos = m >> 2; sl = c * 4 + s;
                    q = pos * 128 + n0 + col;
                    lds[12288 + sl * 1024 + (q ^ ((sl & 7) << 3))] = f2bf(lrelu(acc1[r]));
                }
            }
        }
        __syncthreads();
    }

    // ================= stage hx -> bf16 HX region ==========================
    #pragma unroll
    for (int i = 0; i < 12; ++i) {
        int f = i * 256 + tid;
        int s = f / 192, j = f - s * 192;
        lds[3072 + s * 192 + (j ^ ((s & 7) << 3))] = f2bf(hx[(S0 + s) * 192 + j]);
    }

    // ================= stem: M=16 (row=sample=col), N=192, K=1024 ==========
    {
        f4 acc[3] = {{0.f,0.f,0.f,0.f}, {0.f,0.f,0.f,0.f}, {0.f,0.f,0.f,0.f}};
        int abase = 12288 + col * 1024;
        int sw = (col & 7) << 3;
        const unsigned short* wp = ws + 92160 + (wave * 48 + col) * 1024;
        #pragma unroll 4
        for (int ks = 0; ks < 32; ++ks) {
            int k0 = ks * 32 + quad * 8;
            bf8 a  = *(const bf8*)&lds[abase + (k0 ^ sw)];
            bf8 b0 = *(const bf8*)(wp + k0);
            bf8 b1 = *(const bf8*)(wp + 16 * 1024 + k0);
            bf8 b2 = *(const bf8*)(wp + 32 * 1024 + k0);
            acc[0] = MFMA(a, b0, acc[0]);
            acc[1] = MFMA(a, b1, acc[1]);
            acc[2] = MFMA(a, b2, acc[2]);
        }
        // epilogue: + v_proj + bias, lrelu -> FUSED
        #pragma unroll
        for (int t = 0; t < 3; ++t) {
            int n = wave * 48 + t * 16 + col;
            float bv = bvp[n];
            float wv[9];
            #pragma unroll
            for (int k = 0; k < 9; ++k) wv[k] = wvp[n * 9 + k];
            #pragma unroll
            for (int r = 0; r < 4; ++r) {
                int s = quad * 4 + r;
                const float* vp = v + (S0 + s) * 9;
                float st = bv;
                #pragma unroll
                for (int k = 0; k < 9; ++k) st += vp[k] * wv[k];
                float val = lrelu(acc[t][r] + st);
                lds[s * 192 + (n ^ ((s & 7) << 3))] = f2bf(val);
            }
        }
    }
    __syncthreads();

    // ================= GRU: each wave owns matching r/z/n col tiles ========
    {
        #pragma unroll
        for (int t = 0; t < 3; ++t) {
            int j0 = (wave * 3 + t) * 16;
            const unsigned short* wihp = ws + 288768 + (j0 + col) * 192;
            const unsigned short* whhp = ws + 399360 + (j0 + col) * 192;
            f4 air = {0.f,0.f,0.f,0.f};
            f4 aiz = air, ain = air, ahr = air, ahz = air, ahn = air;
            int fbase = col * 192, hbase = 3072 + col * 192;
            int sw = (col & 7) << 3;
            #pragma unroll
            for (int ks = 0; ks < 6; ++ks) {
                int k0 = ks * 32 + quad * 8;
                bf8 aF = *(const bf8*)&lds[fbase + (k0 ^ sw)];
                bf8 aH = *(const bf8*)&lds[hbase + (k0 ^ sw)];
                bf8 bir = *(const bf8*)(wihp + k0);
                bf8 bhr = *(const bf8*)(whhp + k0);
                bf8 biz = *(const bf8*)(wihp + 192 * 192 + k0);
                bf8 bhz = *(const bf8*)(whhp + 192 * 192 + k0);
                bf8 bin = *(const bf8*)(wihp + 384 * 192 + k0);
                bf8 bhn = *(const bf8*)(whhp + 384 * 192 + k0);
                air = MFMA(aF, bir, air);
                ahr = MFMA(aH, bhr, ahr);
                aiz = MFMA(aF, biz, aiz);
                ahz = MFMA(aH, bhz, ahz);
                ain = MFMA(aF, bin, ain);
                ahn = MFMA(aH, bhn, ahn);
            }
            int j = j0 + col;
            float b_ir = bih[j], b_iz = bih[192 + j], b_in = bih[384 + j];
            float b_hr = bhh[j], b_hz = bhh[192 + j], b_hn = bhh[384 + j];
            #pragma unroll
            for (int r = 0; r < 4; ++r) {
                int s = quad * 4 + r;
                float rg = sigm(air[r] + b_ir + ahr[r] + b_hr);
                float zg = sigm(aiz[r] + b_iz + ahz[r] + b_hz);
                float ng = tanh_(ain[r] + b_in + rg * (ahn[r] + b_hn));
                float hxv = hx[(S0 + s) * 192 + j];
                float hnew = (1.f - zg) * ng + zg * hxv;
                out[65536 * 4 + (S0 + s) * 192 + j] = hnew;
                lds[6144 + s * 192 + (j ^ ((s & 7) << 3))] = f2bf(lrelu(hnew));
            }
        }
    }
    __syncthreads();

    // ================= fc head: act[s][a] = lrelu(hx')@wfc.T ===============
    {
        int s = tid >> 4, aa = (tid >> 2) & 3, part = tid & 3;
        int sw = (s & 7) << 3;
        const float* wf = wfc + aa * 192;
        float sum = 0.f;
        #pragma unroll 8
        for (int jj = 0; jj < 48; ++jj) {
            int j = part * 48 + jj;
            sum += bf2f(lds[6144 + s * 192 + (j ^ sw)]) * wf[j];
        }
        sum += __shfl_xor(sum, 1);
        sum += __shfl_xor(sum, 2);
        if (part == 0) out[(S0 + s) * 4 + aa] = sum;
    }
}

// ---------------------------------------------------------------------------
extern "C" void kernel_launch(void* const* d_in, const int* in_sizes, int n_in,
                              void* d_out, int out_size, void* d_ws, size_t ws_size,
                              hipStream_t stream) {
    const float* x     = (const float*)d_in[0];
    const float* v     = (const float*)d_in[1];
    const float* hx    = (const float*)d_in[2];
    const float* w1    = (const float*)d_in[3];
    const float* w2    = (const float*)d_in[4];
    const float* w3    = (const float*)d_in[5];
    const float* wstem = (const float*)d_in[6];
    const float* wvp   = (const float*)d_in[7];
    const float* bvp   = (const float*)d_in[8];
    const float* wih   = (const float*)d_in[9];
    const float* whh   = (const float*)d_in[10];
    const float* bih   = (const float*)d_in[11];
    const float* bhh   = (const float*)d_in[12];
    const float* wfc   = (const float*)d_in[13];
    unsigned short* wsp = (unsigned short*)d_ws;

    prep_weights<<<1992, 256, 0, stream>>>(w2, w3, wstem, wih, whh, wsp);
    fused_model<<<4096, 256, 0, stream>>>(x, v, hx, w1, wvp, bvp, bih, bhh, wfc,
                                          wsp, (float*)d_out);
}